// Round 11
// baseline (130.387 us; speedup 1.0000x reference)
//
#include <hip/hip_runtime.h>
#include <hip/hip_bf16.h>

#define N_SAMP   1024
#define BD       2048
#define LATENT_D 1024
#define NCLS     64
#define HW       49

typedef __attribute__((ext_vector_type(8))) _Float16 f16x8;
typedef __attribute__((ext_vector_type(4))) float f32x4;
typedef unsigned short u16;

// ---------------------------------------------------------------------------
// Split-fp16 tiled+swizzled layout (rounds 2-10, verified):
//   segment (kg = k>>5, row) = 32 ushorts (64 B) at ((kg*rows + row)*32),
//   byte within segment: c2 = (ke*2) ^ (((row>>1)&3)<<4).
// Linear global_load_lds lands pre-swizzled for conflict-light ds_read_b128.
// fp16 2-way split, 3 products (a0b0+a0b1+a1b0): ~5e-8 logit error, fp32-grade.
// Round-9 lesson: cross-XCD threadfence reduction regressed 126->199 us;
// per-XCD L2 non-coherence makes device-scope fences expensive (G16).
// Round-11: reduce+cls+decode+expert fused into one tail kernel; X/x/part2
// intermediates never touch global memory.
// ---------------------------------------------------------------------------
__device__ __forceinline__ size_t split_idx_r(int row, int k, int rows) {
    const int kg = k >> 5, ke = k & 31;
    const int c2 = (ke * 2) ^ (((row >> 1) & 3) << 4);
    return ((size_t)(kg * rows + row) * 32) + (c2 >> 1);
}

__device__ __forceinline__ void split2(float v, u16* p0, u16* p1, size_t idx) {
    _Float16 h0 = (_Float16)v;
    _Float16 h1 = (_Float16)(v - (float)h0);
    p0[idx] = *(u16*)&h0;
    p1[idx] = *(u16*)&h1;
}

#define GLL16(g, l) __builtin_amdgcn_global_load_lds( \
    (const __attribute__((address_space(1))) void*)(g), \
    (__attribute__((address_space(3))) void*)(l), 16, 0, 0)

// ---------------------------------------------------------------------------
// Kernel 1 (fused prep):
//  [0, 8192):      avg-pool 7x7 -> split2 -> A0/A1 (rows=1024, K=2048)
//  [8192, 16384):  fc1_w split -> B0/B1
//  [16384, 16896): cls weights [64 pos | 64 orient] -> C0/C1 (rows=128)
// ---------------------------------------------------------------------------
__global__ __launch_bounds__(256) void prep_kernel(const float* __restrict__ feat,
                                                   const float* __restrict__ W,
                                                   const float* __restrict__ Wp,
                                                   const float* __restrict__ Wo,
                                                   u16* __restrict__ a0,
                                                   u16* __restrict__ a1,
                                                   u16* __restrict__ b0,
                                                   u16* __restrict__ b1,
                                                   u16* __restrict__ c0,
                                                   u16* __restrict__ c1) {
    __shared__ float buf[256 * HW];                  // 50176 B (pool blocks only)
    const int b = blockIdx.x;
    const int tid = threadIdx.x;
    if (b < 8192) {
        const int lane = tid & 63, wv = tid >> 6;
        const float* src = feat + (size_t)b * (256 * HW);
        for (int c = wv; c < 49; c += 4)
            GLL16(src + c * 256 + lane * 4, (char*)buf + c * 1024 + lane * 16);
        asm volatile("s_waitcnt vmcnt(0)" ::: "memory");
        __syncthreads();
        const float* p = buf + tid * HW;
        float s = 0.f;
        #pragma unroll
        for (int k = 0; k < HW; ++k) s += p[k];
        const float v = s * (1.0f / 49.0f);
        const int n = b >> 3;
        const int d = (b & 7) * 256 + tid;
        split2(v, a0, a1, split_idx_r(n, d, N_SAMP));
    } else if (b < 16384) {
        const int b2 = b - 8192;
        const int row = b2 >> 3;
        const int d = (b2 & 7) * 256 + tid;
        split2(W[(size_t)row * BD + d], b0, b1, split_idx_r(row, d, LATENT_D));
    } else {
        const int b2 = b - 16384;
        const int row = b2 >> 2;                            // 0..127
        const int d = (b2 & 3) * 256 + tid;                 // 0..1023
        const float v = row < 64 ? Wp[(size_t)row * LATENT_D + d]
                                 : Wo[(size_t)(row - 64) * LATENT_D + d];
        split2(v, c0, c1, split_idx_r(row, d, 128));
    }
}

// ---------------------------------------------------------------------------
// Kernel 2: fc1 split-fp16 MFMA GEMM, 3 products, counted-vmcnt (verified).
// Tile 128x128, BK=32, nsplit=4, XCD-bijective swizzle (nwg=256, %8==0).
// ---------------------------------------------------------------------------
__global__ __launch_bounds__(256, 2) void split_mfma(
    const u16* __restrict__ A0, const u16* __restrict__ A1,
    const u16* __restrict__ B0, const u16* __restrict__ B1,
    float* __restrict__ part, int ksteps, int rowsA, int rowsB, int ldc) {
    __shared__ u16 lds[2][4 * 4096];   // 2 phases x (A0|A1|B0|B1) x 8 KB
    const int nwg = gridDim.x * gridDim.y * gridDim.z;
    const int flat = blockIdx.x + gridDim.x * (blockIdx.y + gridDim.y * blockIdx.z);
    const int chunk = nwg >> 3;
    const int swz = (flat & 7) * chunk + (flat >> 3);
    const int bn = swz % gridDim.x;
    const int rest = swz / gridDim.x;
    const int bm = rest % gridDim.y;
    const int kz = rest / gridDim.y;

    const int tid = threadIdx.x, lane = tid & 63, wv = tid >> 6;
    const int wrow = (wv >> 1) * 64, wcol = (wv & 1) * 64;
    const int r15 = lane & 15, khi = lane >> 4;

    const u16* gA[2] = {A0, A1};
    const u16* gB[2] = {B0, B1};
    const int kg0 = kz * ksteps;

    auto stage = [&](int kg, int buf) {
        #pragma unroll
        for (int s = 0; s < 2; ++s) {
            const u16* g = gA[s] + ((size_t)(kg * rowsA + bm * 128 + wv * 32) * 32) + lane * 8;
            u16* l = &lds[buf][s * 4096 + wv * 1024 + lane * 8];
            GLL16(g, l);
            GLL16(g + 512, l + 512);
        }
        #pragma unroll
        for (int s = 0; s < 2; ++s) {
            const u16* g = gB[s] + ((size_t)(kg * rowsB + bn * 128 + wv * 32) * 32) + lane * 8;
            u16* l = &lds[buf][(2 + s) * 4096 + wv * 1024 + lane * 8];
            GLL16(g, l);
            GLL16(g + 512, l + 512);
        }
    };

    f32x4 acc[4][4];
    #pragma unroll
    for (int i = 0; i < 4; ++i)
        #pragma unroll
        for (int j = 0; j < 4; ++j) acc[i][j] = (f32x4){0.f, 0.f, 0.f, 0.f};

    stage(kg0, 0);

    int cur = 0;
    for (int ks = 0; ks < ksteps; ++ks) {
        if (ks + 1 < ksteps) {
            stage(kg0 + ks + 1, cur ^ 1);
            asm volatile("s_waitcnt vmcnt(8)" ::: "memory");
        } else {
            asm volatile("s_waitcnt vmcnt(0)" ::: "memory");
        }
        __builtin_amdgcn_s_barrier();
        __builtin_amdgcn_sched_barrier(0);
        f16x8 af[4][2], bf[4][2];
        #pragma unroll
        for (int i = 0; i < 4; ++i) {
            const int rowA = wrow + i * 16 + r15;
            const int offA = rowA * 64 + ((khi * 16) ^ (((rowA >> 1) & 3) << 4));
            const int rowB = wcol + i * 16 + r15;
            const int offB = rowB * 64 + ((khi * 16) ^ (((rowB >> 1) & 3) << 4));
            #pragma unroll
            for (int s = 0; s < 2; ++s) {
                af[i][s] = *(const f16x8*)((const char*)&lds[cur][s * 4096] + offA);
                bf[i][s] = *(const f16x8*)((const char*)&lds[cur][(2 + s) * 4096] + offB);
            }
        }
        #pragma unroll
        for (int p = 0; p < 3; ++p) {
            const int pa = (p == 2) ? 1 : 0;
            const int pb = (p == 1) ? 1 : 0;
            #pragma unroll
            for (int i = 0; i < 4; ++i)
                #pragma unroll
                for (int j = 0; j < 4; ++j)
                    acc[i][j] = __builtin_amdgcn_mfma_f32_16x16x32_f16(
                        af[i][pa], bf[j][pb], acc[i][j], 0, 0, 0);
        }
        __builtin_amdgcn_s_barrier();
        cur ^= 1;
    }

    float* pt = part + (size_t)kz * ((size_t)N_SAMP * ldc);
    #pragma unroll
    for (int i = 0; i < 4; ++i) {
        const int row0 = bm * 128 + wrow + i * 16 + khi * 4;
        #pragma unroll
        for (int j = 0; j < 4; ++j) {
            const int col = bn * 128 + wcol + j * 16 + r15;
            #pragma unroll
            for (int q = 0; q < 4; ++q)
                pt[(size_t)(row0 + q) * ldc + col] = acc[i][j][q];
        }
    }
}

// ---------------------------------------------------------------------------
// Kernel 3 (fused tail): reduce fc1 partials + bias + ReLU + cls GEMM +
// sigmoid + ordinal decode + expert heads. Block = 4 samples, 256 threads.
// Phase 1: reduce 4 rows of partials -> xf (fp32 LDS) + xs0/xs1 (fp16 splits).
// Phase 2: cls logits via 3-product MFMA; A-frag rows read clamped (r15&3):
//   duplicated A rows only affect D rows 4-15 (ignored); D rows 0-3 = samples
//   (sample = q at khi==0, per verified C/D mapping). B = C0/C1 staged with
//   the verified counted-vmcnt loop (4 GLL16/wave -> vmcnt(4)).
// Phase 3: logits -> LDS; ballot decode (2 waves); expert matvecs from xf.
// No intermediate global buffers; saves ~24 MB traffic + 2 launches.
// ---------------------------------------------------------------------------
__global__ __launch_bounds__(256) void tail_kernel(
    const float* __restrict__ part, int nsplit,
    const float* __restrict__ fc1_b,
    const u16* __restrict__ C0, const u16* __restrict__ C1,
    const float* __restrict__ cpb, const float* __restrict__ cob,
    const float* __restrict__ wpos, const float* __restrict__ bpos,
    const float* __restrict__ wori, const float* __restrict__ bori,
    float* __restrict__ pose, float* __restrict__ pose_cls) {
    __shared__ u16 xs0[4][1024];        // 8 KB  h0 splits
    __shared__ u16 xs1[4][1024];        // 8 KB  h1 splits
    __shared__ float xf[4][1024];       // 16 KB fp32 x rows
    __shared__ u16 cl[2][2][4096];      // 32 KB C-tile dbuf [buf][split][128*32]
    __shared__ float lg[4][128];        // 2 KB  logits
    __shared__ int esh[4][2];

    const int b = blockIdx.x;           // 256 blocks x 4 samples
    const int tid = threadIdx.x, lane = tid & 63, wv = tid >> 6;
    const int r15 = lane & 15, khi = lane >> 4;
    const int row0 = b * 4;

    auto stageC = [&](int kg, int buf) {
        const u16* g0 = C0 + (size_t)kg * 4096 + tid * 8;
        GLL16(g0, &cl[buf][0][tid * 8]);
        GLL16(g0 + 2048, &cl[buf][0][tid * 8 + 2048]);
        const u16* g1 = C1 + (size_t)kg * 4096 + tid * 8;
        GLL16(g1, &cl[buf][1][tid * 8]);
        GLL16(g1 + 2048, &cl[buf][1][tid * 8 + 2048]);
    };

    // issue first C-tile early; completes during phase 1
    stageC(0, 0);

    // ---- phase 1: reduce partials + bias + relu -> xf, xs0/xs1
    #pragma unroll
    for (int i = 0; i < 4; ++i) {
        const int f = tid + 256 * i;               // float4 id, 1024 total
        const int r = f >> 8, c4 = f & 255;
        const float* pp = part + (size_t)(row0 + r) * LATENT_D + c4 * 4;
        float4 s = *(const float4*)pp;
        for (int z = 1; z < nsplit; ++z) {
            const float4 t2 = *(const float4*)(pp + (size_t)z * (N_SAMP * LATENT_D));
            s.x += t2.x; s.y += t2.y; s.z += t2.z; s.w += t2.w;
        }
        const float4 bb = reinterpret_cast<const float4*>(fc1_b)[c4];
        s.x = fmaxf(s.x + bb.x, 0.f); s.y = fmaxf(s.y + bb.y, 0.f);
        s.z = fmaxf(s.z + bb.z, 0.f); s.w = fmaxf(s.w + bb.w, 0.f);
        *reinterpret_cast<float4*>(&xf[r][c4 * 4]) = s;
        const int k0 = c4 * 4;
        split2(s.x, &xs0[0][0], &xs1[0][0], r * 1024 + k0 + 0);
        split2(s.y, &xs0[0][0], &xs1[0][0], r * 1024 + k0 + 1);
        split2(s.z, &xs0[0][0], &xs1[0][0], r * 1024 + k0 + 2);
        split2(s.w, &xs0[0][0], &xs1[0][0], r * 1024 + k0 + 3);
    }
    __syncthreads();   // xs/xf visible (also drains stageC(0) via compiler vmcnt(0))

    // ---- phase 2: cls logits, K=1024 in 32 steps, counted-vmcnt pipeline
    f32x4 acc[2];
    acc[0] = (f32x4){0.f, 0.f, 0.f, 0.f};
    acc[1] = (f32x4){0.f, 0.f, 0.f, 0.f};
    const int rA = r15 & 3;            // row-clamped A read (D rows 4-15 unused)

    int cur = 0;
    for (int ks = 0; ks < 32; ++ks) {
        if (ks + 1 < 32) {
            stageC(ks + 1, cur ^ 1);
            asm volatile("s_waitcnt vmcnt(4)" ::: "memory");
        } else {
            asm volatile("s_waitcnt vmcnt(0)" ::: "memory");
        }
        __builtin_amdgcn_s_barrier();
        __builtin_amdgcn_sched_barrier(0);
        const int aoff = rA * 2048 + ks * 64 + khi * 16;   // bytes into xs
        const f16x8 a0 = *(const f16x8*)((const char*)xs0 + aoff);
        const f16x8 a1 = *(const f16x8*)((const char*)xs1 + aoff);
        #pragma unroll
        for (int j = 0; j < 2; ++j) {
            const int col = wv * 32 + j * 16 + r15;
            const int offB = col * 64 + ((khi * 16) ^ (((col >> 1) & 3) << 4));
            const f16x8 b0 = *(const f16x8*)((const char*)&cl[cur][0][0] + offB);
            const f16x8 b1 = *(const f16x8*)((const char*)&cl[cur][1][0] + offB);
            acc[j] = __builtin_amdgcn_mfma_f32_16x16x32_f16(a0, b0, acc[j], 0, 0, 0);
            acc[j] = __builtin_amdgcn_mfma_f32_16x16x32_f16(a0, b1, acc[j], 0, 0, 0);
            acc[j] = __builtin_amdgcn_mfma_f32_16x16x32_f16(a1, b0, acc[j], 0, 0, 0);
        }
        __builtin_amdgcn_s_barrier();
        cur ^= 1;
    }

    // ---- logits to LDS: D rows 0-3 (samples) live in lanes 0-15, regs q
    if (lane < 16) {
        #pragma unroll
        for (int j = 0; j < 2; ++j)
            #pragma unroll
            for (int q = 0; q < 4; ++q)
                lg[q][wv * 32 + j * 16 + lane] = acc[j][q];
    }
    __syncthreads();

    // ---- decode: sigmoid + pose_cls + ordinal labels (waves 0-1)
    if (tid < 128) {
        const int head = tid >> 6, c = tid & 63;
        #pragma unroll
        for (int q = 0; q < 4; ++q) {
            const float s = lg[q][tid] + (head ? cob[c] : cpb[c]);
            const float sig = 1.0f / (1.0f + expf(-s));
            pose_cls[(size_t)(row0 + q) * (NCLS * 2) + c * 2 + head] = sig;
            const unsigned long long mask = __ballot(s > 0.0f);
            if (c == 0) {
                const unsigned long long inv = ~mask;
                const int run = inv ? __builtin_ctzll(inv) : 64;
                const int lab = run - 1;
                esh[q][head] = lab > 0 ? lab : 0;
            }
        }
    }
    __syncthreads();

    // ---- expert heads: 28 tasks (4 samples x 7 outputs), wave wv takes
    // tasks wv, wv+4, ...  x read from LDS xf (== h0+h1 within 2^-22).
    for (int task = wv; task < 28; task += 4) {
        const int q = task / 7, k = task % 7;
        const float* wr;
        float bb;
        if (k < 3) {
            const int e = esh[q][0];
            wr = wpos + (size_t)(e * 3 + k) * LATENT_D;
            bb = bpos[e * 3 + k];
        } else {
            const int e = esh[q][1];
            const int kk = k - 3;
            wr = wori + (size_t)(e * 4 + kk) * LATENT_D;
            bb = bori[e * 4 + kk];
        }
        const float4* w4 = reinterpret_cast<const float4*>(wr);
        float s2 = 0.f;
        #pragma unroll
        for (int i = 0; i < 4; ++i) {
            const int qq = lane + i * 64;
            const float4 a = w4[qq];
            s2 += a.x * xf[q][qq * 4] + a.y * xf[q][qq * 4 + 1]
                + a.z * xf[q][qq * 4 + 2] + a.w * xf[q][qq * 4 + 3];
        }
        #pragma unroll
        for (int off = 32; off > 0; off >>= 1) s2 += __shfl_down(s2, off);
        if (lane == 0) pose[(size_t)(row0 + q) * 7 + k] = s2 + bb;
    }
}

// ---------------------------------------------------------------------------
extern "C" void kernel_launch(void* const* d_in, const int* in_sizes, int n_in,
                              void* d_out, int out_size, void* d_ws, size_t ws_size,
                              hipStream_t stream) {
    const float* feat   = (const float*)d_in[0];
    const float* fc1_w  = (const float*)d_in[1];
    const float* fc1_b  = (const float*)d_in[2];
    const float* cpw    = (const float*)d_in[3];
    const float* cpb    = (const float*)d_in[4];
    const float* cow    = (const float*)d_in[5];
    const float* cob    = (const float*)d_in[6];
    const float* rpw    = (const float*)d_in[7];
    const float* rpb    = (const float*)d_in[8];
    const float* row_   = (const float*)d_in[9];
    const float* rob    = (const float*)d_in[10];

    float* out = (float*)d_out;
    float* pose     = out;                          // [1024][7]
    float* pose_cls = out + (size_t)N_SAMP * 7;     // [1024][64][2]

    char* ws = (char*)d_ws;
    const size_t MB = (size_t)1 << 20;
    size_t off = 0;
    auto take = [&](size_t bytes) { char* p = ws + off; off += (bytes + 255) & ~(size_t)255; return p; };

    u16* A0 = (u16*)take(4 * MB);      // 64kg x 1024 x 32 x 2B
    u16* A1 = (u16*)take(4 * MB);
    u16* B0 = (u16*)take(4 * MB);
    u16* B1 = (u16*)take(4 * MB);
    u16* C0 = (u16*)take(256 * 1024);  // 32kg x 128 x 32 x 2B
    u16* C1 = (u16*)take(256 * 1024);

    int nsplit = 4;
    while (nsplit > 1 && off + (size_t)nsplit * 4 * MB > ws_size) nsplit >>= 1;
    float* part = (float*)take((size_t)nsplit * 4 * MB);

    // 1. fused prep: pool->A splits, fc1_w->B splits, cls->C splits
    prep_kernel<<<16896, 256, 0, stream>>>(feat, fc1_w, cpw, cow,
                                           A0, A1, B0, B1, C0, C1);
    // 2. fc1: M=1024, N=1024, K=2048  (grid (8,8,4)=256 blocks, %8==0)
    split_mfma<<<dim3(8, 8, nsplit), 256, 0, stream>>>(
        A0, A1, B0, B1, part, 64 / nsplit, N_SAMP, LATENT_D, LATENT_D);
    // 3. fused tail: reduce + cls GEMM + decode + expert
    tail_kernel<<<256, 256, 0, stream>>>(part, nsplit, fc1_b, C0, C1,
                                         cpb, cob, rpw, rpb, row_, rob,
                                         pose, pose_cls);
}

// Round 12
// 123.709 us; speedup vs baseline: 1.0540x; 1.0540x over previous
//
#include <hip/hip_runtime.h>
#include <hip/hip_bf16.h>

#define N_SAMP   1024
#define BD       2048
#define LATENT_D 1024
#define NCLS     64
#define HW       49

typedef __attribute__((ext_vector_type(8))) _Float16 f16x8;
typedef __attribute__((ext_vector_type(4))) float f32x4;
typedef unsigned short u16;

// ---------------------------------------------------------------------------
// Split-fp16 tiled+swizzled layout (rounds 2-10, verified):
//   segment (kg = k>>5, row) = 32 ushorts (64 B) at ((kg*rows + row)*32),
//   byte within segment: c2 = (ke*2) ^ (((row>>1)&3)<<4).
// Linear global_load_lds lands pre-swizzled for conflict-light ds_read_b128.
// fp16 2-way split, 3 products (a0b0+a0b1+a1b0): ~5e-8 logit error, fp32-grade.
// Round-9 lesson: cross-XCD threadfence reduction regressed 126->199 us
// (per-XCD L2 non-coherent, G16) — separate reduce kernel is cheaper.
// Round-11 lesson: fusing reduce+cls+decode into one kernel regressed
// 124->130 us — 1 block/CU barrier-bound cls loop + 256x duplicated C
// staging (128 MB) outweighs 24 MB traffic + 2 launch savings. Fusions must
// not serialize a GEMM into a single-block-per-CU barrier loop.
// This file = round-10 configuration (verified best: 123.8 us).
// ---------------------------------------------------------------------------
__device__ __forceinline__ size_t split_idx_r(int row, int k, int rows) {
    const int kg = k >> 5, ke = k & 31;
    const int c2 = (ke * 2) ^ (((row >> 1) & 3) << 4);
    return ((size_t)(kg * rows + row) * 32) + (c2 >> 1);
}

__device__ __forceinline__ void split2(float v, u16* p0, u16* p1, size_t idx) {
    _Float16 h0 = (_Float16)v;
    _Float16 h1 = (_Float16)(v - (float)h0);
    p0[idx] = *(u16*)&h0;
    p1[idx] = *(u16*)&h1;
}

#define GLL16(g, l) __builtin_amdgcn_global_load_lds( \
    (const __attribute__((address_space(1))) void*)(g), \
    (__attribute__((address_space(3))) void*)(l), 16, 0, 0)

// ---------------------------------------------------------------------------
// Kernel 1 (fused prep):
//  [0, 8192):      avg-pool 7x7 -> split2 -> A0/A1 (rows=1024, K=2048)
//  [8192, 16384):  fc1_w split -> B0/B1
//  [16384, 16896): cls weights [64 pos | 64 orient] -> C0/C1 (rows=128)
// ---------------------------------------------------------------------------
__global__ __launch_bounds__(256) void prep_kernel(const float* __restrict__ feat,
                                                   const float* __restrict__ W,
                                                   const float* __restrict__ Wp,
                                                   const float* __restrict__ Wo,
                                                   u16* __restrict__ a0,
                                                   u16* __restrict__ a1,
                                                   u16* __restrict__ b0,
                                                   u16* __restrict__ b1,
                                                   u16* __restrict__ c0,
                                                   u16* __restrict__ c1) {
    __shared__ float buf[256 * HW];                  // 50176 B (pool blocks only)
    const int b = blockIdx.x;
    const int tid = threadIdx.x;
    if (b < 8192) {
        const int lane = tid & 63, wv = tid >> 6;
        const float* src = feat + (size_t)b * (256 * HW);
        for (int c = wv; c < 49; c += 4)
            GLL16(src + c * 256 + lane * 4, (char*)buf + c * 1024 + lane * 16);
        asm volatile("s_waitcnt vmcnt(0)" ::: "memory");
        __syncthreads();
        const float* p = buf + tid * HW;
        float s = 0.f;
        #pragma unroll
        for (int k = 0; k < HW; ++k) s += p[k];
        const float v = s * (1.0f / 49.0f);
        const int n = b >> 3;
        const int d = (b & 7) * 256 + tid;
        split2(v, a0, a1, split_idx_r(n, d, N_SAMP));
    } else if (b < 16384) {
        const int b2 = b - 8192;
        const int row = b2 >> 3;
        const int d = (b2 & 7) * 256 + tid;
        split2(W[(size_t)row * BD + d], b0, b1, split_idx_r(row, d, LATENT_D));
    } else {
        const int b2 = b - 16384;
        const int row = b2 >> 2;                            // 0..127
        const int d = (b2 & 3) * 256 + tid;                 // 0..1023
        const float v = row < 64 ? Wp[(size_t)row * LATENT_D + d]
                                 : Wo[(size_t)(row - 64) * LATENT_D + d];
        split2(v, c0, c1, split_idx_r(row, d, 128));
    }
}

// ---------------------------------------------------------------------------
// Kernel 2: fc1 split-fp16 MFMA GEMM, 3 products, counted-vmcnt pipeline (T4).
// Tile 128x128, BK=32, 4 waves x (64x64 quadrant of 4x4 16x16x32 frags).
// Per K-step: stage(t+1) [8 loads] -> vmcnt(8) waits only tile t's loads
// -> barrier -> sched_barrier (rule #18) -> ds_read+MFMA -> barrier.
// Final iter: vmcnt(0). XCD-bijective swizzle (nwg%8==0). nsplit=4.
// ---------------------------------------------------------------------------
__global__ __launch_bounds__(256, 2) void split_mfma(
    const u16* __restrict__ A0, const u16* __restrict__ A1,
    const u16* __restrict__ B0, const u16* __restrict__ B1,
    float* __restrict__ part, int ksteps, int rowsA, int rowsB, int ldc) {
    __shared__ u16 lds[2][4 * 4096];   // 2 phases x (A0|A1|B0|B1) x 8 KB
    const int nwg = gridDim.x * gridDim.y * gridDim.z;
    const int flat = blockIdx.x + gridDim.x * (blockIdx.y + gridDim.y * blockIdx.z);
    const int chunk = nwg >> 3;
    const int swz = (flat & 7) * chunk + (flat >> 3);
    const int bn = swz % gridDim.x;
    const int rest = swz / gridDim.x;
    const int bm = rest % gridDim.y;
    const int kz = rest / gridDim.y;

    const int tid = threadIdx.x, lane = tid & 63, wv = tid >> 6;
    const int wrow = (wv >> 1) * 64, wcol = (wv & 1) * 64;
    const int r15 = lane & 15, khi = lane >> 4;

    const u16* gA[2] = {A0, A1};
    const u16* gB[2] = {B0, B1};
    const int kg0 = kz * ksteps;

    auto stage = [&](int kg, int buf) {
        #pragma unroll
        for (int s = 0; s < 2; ++s) {
            const u16* g = gA[s] + ((size_t)(kg * rowsA + bm * 128 + wv * 32) * 32) + lane * 8;
            u16* l = &lds[buf][s * 4096 + wv * 1024 + lane * 8];
            GLL16(g, l);
            GLL16(g + 512, l + 512);
        }
        #pragma unroll
        for (int s = 0; s < 2; ++s) {
            const u16* g = gB[s] + ((size_t)(kg * rowsB + bn * 128 + wv * 32) * 32) + lane * 8;
            u16* l = &lds[buf][(2 + s) * 4096 + wv * 1024 + lane * 8];
            GLL16(g, l);
            GLL16(g + 512, l + 512);
        }
    };

    f32x4 acc[4][4];
    #pragma unroll
    for (int i = 0; i < 4; ++i)
        #pragma unroll
        for (int j = 0; j < 4; ++j) acc[i][j] = (f32x4){0.f, 0.f, 0.f, 0.f};

    stage(kg0, 0);   // tile 0; counted wait happens in iter 0

    int cur = 0;
    for (int ks = 0; ks < ksteps; ++ks) {
        if (ks + 1 < ksteps) {
            stage(kg0 + ks + 1, cur ^ 1);                     // 8 more in flight
            asm volatile("s_waitcnt vmcnt(8)" ::: "memory");  // tile ks landed
        } else {
            asm volatile("s_waitcnt vmcnt(0)" ::: "memory");
        }
        __builtin_amdgcn_s_barrier();
        __builtin_amdgcn_sched_barrier(0);
        f16x8 af[4][2], bf[4][2];
        #pragma unroll
        for (int i = 0; i < 4; ++i) {
            const int rowA = wrow + i * 16 + r15;
            const int offA = rowA * 64 + ((khi * 16) ^ (((rowA >> 1) & 3) << 4));
            const int rowB = wcol + i * 16 + r15;
            const int offB = rowB * 64 + ((khi * 16) ^ (((rowB >> 1) & 3) << 4));
            #pragma unroll
            for (int s = 0; s < 2; ++s) {
                af[i][s] = *(const f16x8*)((const char*)&lds[cur][s * 4096] + offA);
                bf[i][s] = *(const f16x8*)((const char*)&lds[cur][(2 + s) * 4096] + offB);
            }
        }
        #pragma unroll
        for (int p = 0; p < 3; ++p) {
            const int pa = (p == 2) ? 1 : 0;
            const int pb = (p == 1) ? 1 : 0;
            #pragma unroll
            for (int i = 0; i < 4; ++i)
                #pragma unroll
                for (int j = 0; j < 4; ++j)
                    acc[i][j] = __builtin_amdgcn_mfma_f32_16x16x32_f16(
                        af[i][pa], bf[j][pb], acc[i][j], 0, 0, 0);
        }
        __builtin_amdgcn_s_barrier();
        cur ^= 1;
    }

    float* pt = part + (size_t)kz * ((size_t)N_SAMP * ldc);
    #pragma unroll
    for (int i = 0; i < 4; ++i) {
        const int row0 = bm * 128 + wrow + i * 16 + khi * 4;
        #pragma unroll
        for (int j = 0; j < 4; ++j) {
            const int col = bn * 128 + wcol + j * 16 + r15;
            #pragma unroll
            for (int q = 0; q < 4; ++q)
                pt[(size_t)(row0 + q) * ldc + col] = acc[i][j][q];
        }
    }
}

// ---------------------------------------------------------------------------
// Kernel 2b: cls GEMM, 64x64 tiles, counted-vmcnt pipeline (vmcnt(4)).
// nsplit_c=4 -> grid (2,16,4) = 128 blocks (%8==0).
// ---------------------------------------------------------------------------
__global__ __launch_bounds__(256, 4) void cls_mfma(
    const u16* __restrict__ A0, const u16* __restrict__ A1,
    const u16* __restrict__ B0, const u16* __restrict__ B1,
    float* __restrict__ part, int ksteps) {
    __shared__ u16 lds[2][4 * 2048];
    const int nwg = gridDim.x * gridDim.y * gridDim.z;
    const int flat = blockIdx.x + gridDim.x * (blockIdx.y + gridDim.y * blockIdx.z);
    const int chunk = nwg >> 3;
    const int swz = (flat & 7) * chunk + (flat >> 3);
    const int bn = swz % gridDim.x;
    const int rest = swz / gridDim.x;
    const int bm = rest % gridDim.y;
    const int kz = rest / gridDim.y;

    const int tid = threadIdx.x, lane = tid & 63, wv = tid >> 6;
    const int wrow = (wv >> 1) * 32, wcol = (wv & 1) * 32;
    const int r15 = lane & 15, khi = lane >> 4;

    const u16* gA[2] = {A0, A1};
    const u16* gB[2] = {B0, B1};
    const int kg0 = kz * ksteps;

    auto stage = [&](int kg, int buf) {
        #pragma unroll
        for (int s = 0; s < 2; ++s) {
            const u16* g = gA[s] + ((size_t)(kg * 1024 + bm * 64 + wv * 16) * 32) + lane * 8;
            GLL16(g, &lds[buf][s * 2048 + wv * 512 + lane * 8]);
        }
        #pragma unroll
        for (int s = 0; s < 2; ++s) {
            const u16* g = gB[s] + ((size_t)(kg * 128 + bn * 64 + wv * 16) * 32) + lane * 8;
            GLL16(g, &lds[buf][(2 + s) * 2048 + wv * 512 + lane * 8]);
        }
    };

    f32x4 acc[2][2];
    #pragma unroll
    for (int i = 0; i < 2; ++i)
        #pragma unroll
        for (int j = 0; j < 2; ++j) acc[i][j] = (f32x4){0.f, 0.f, 0.f, 0.f};

    stage(kg0, 0);

    int cur = 0;
    for (int ks = 0; ks < ksteps; ++ks) {
        if (ks + 1 < ksteps) {
            stage(kg0 + ks + 1, cur ^ 1);
            asm volatile("s_waitcnt vmcnt(4)" ::: "memory");
        } else {
            asm volatile("s_waitcnt vmcnt(0)" ::: "memory");
        }
        __builtin_amdgcn_s_barrier();
        __builtin_amdgcn_sched_barrier(0);
        f16x8 af[2][2], bf[2][2];
        #pragma unroll
        for (int i = 0; i < 2; ++i) {
            const int rowA = wrow + i * 16 + r15;
            const int offA = rowA * 64 + ((khi * 16) ^ (((rowA >> 1) & 3) << 4));
            const int rowB = wcol + i * 16 + r15;
            const int offB = rowB * 64 + ((khi * 16) ^ (((rowB >> 1) & 3) << 4));
            #pragma unroll
            for (int s = 0; s < 2; ++s) {
                af[i][s] = *(const f16x8*)((const char*)&lds[cur][s * 2048] + offA);
                bf[i][s] = *(const f16x8*)((const char*)&lds[cur][(2 + s) * 2048] + offB);
            }
        }
        #pragma unroll
        for (int p = 0; p < 3; ++p) {
            const int pa = (p == 2) ? 1 : 0;
            const int pb = (p == 1) ? 1 : 0;
            #pragma unroll
            for (int i = 0; i < 2; ++i)
                #pragma unroll
                for (int j = 0; j < 2; ++j)
                    acc[i][j] = __builtin_amdgcn_mfma_f32_16x16x32_f16(
                        af[i][pa], bf[j][pb], acc[i][j], 0, 0, 0);
        }
        __builtin_amdgcn_s_barrier();
        cur ^= 1;
    }

    float* pt = part + (size_t)kz * ((size_t)N_SAMP * 128);
    #pragma unroll
    for (int i = 0; i < 2; ++i) {
        const int row0 = bm * 64 + wrow + i * 16 + khi * 4;
        #pragma unroll
        for (int j = 0; j < 2; ++j) {
            const int col = bn * 64 + wcol + j * 16 + r15;
            #pragma unroll
            for (int q = 0; q < 4; ++q)
                pt[(size_t)(row0 + q) * 128 + col] = acc[i][j][q];
        }
    }
}

// ---------------------------------------------------------------------------
// Kernel 3: reduce fc1 split-K partials + bias + ReLU -> x fp32, and split2
// x into swizzled X0/X1 (rows=1024, K=1024) for the cls GEMM.
// ---------------------------------------------------------------------------
__global__ __launch_bounds__(256) void reduce_fc1(const float* __restrict__ part,
                                                  const float* __restrict__ bias,
                                                  float* __restrict__ x,
                                                  u16* __restrict__ x0,
                                                  u16* __restrict__ x1,
                                                  int nsplit) {
    const int i = blockIdx.x * 256 + threadIdx.x;     // float4 index, 262144 total
    const float4* p = reinterpret_cast<const float4*>(part);
    float4 s = p[i];
    for (int z = 1; z < nsplit; ++z) {
        const float4 t = p[(size_t)z * 262144 + i];
        s.x += t.x; s.y += t.y; s.z += t.z; s.w += t.w;
    }
    const float4 b = reinterpret_cast<const float4*>(bias)[i & 255];
    s.x = fmaxf(s.x + b.x, 0.f); s.y = fmaxf(s.y + b.y, 0.f);
    s.z = fmaxf(s.z + b.z, 0.f); s.w = fmaxf(s.w + b.w, 0.f);
    reinterpret_cast<float4*>(x)[i] = s;
    const int n = i >> 8, d0 = (i & 255) * 4;
    split2(s.x, x0, x1, split_idx_r(n, d0 + 0, N_SAMP));
    split2(s.y, x0, x1, split_idx_r(n, d0 + 1, N_SAMP));
    split2(s.z, x0, x1, split_idx_r(n, d0 + 2, N_SAMP));
    split2(s.w, x0, x1, split_idx_r(n, d0 + 3, N_SAMP));
}

// ---------------------------------------------------------------------------
// Kernel 4: fused decode + expert (verified rounds 4-10). Block per sample.
// ---------------------------------------------------------------------------
__global__ __launch_bounds__(128) void decode_expert(const float* __restrict__ part2,
                                                     const float* __restrict__ bp,
                                                     const float* __restrict__ bo,
                                                     const float* __restrict__ x,
                                                     const float* __restrict__ wpos,
                                                     const float* __restrict__ bpos,
                                                     const float* __restrict__ wori,
                                                     const float* __restrict__ bori,
                                                     float* __restrict__ pose_cls,
                                                     float* __restrict__ pose,
                                                     int nsplit) {
    const int n = blockIdx.x, t = threadIdx.x;
    __shared__ float xs[LATENT_D];
    __shared__ int esh[2];

    const float4* x4 = reinterpret_cast<const float4*>(x + (size_t)n * LATENT_D);
    float4* xs4 = reinterpret_cast<float4*>(xs);
    xs4[t] = x4[t];
    xs4[t + 128] = x4[t + 128];

    float s = (t < 64) ? bp[t] : bo[t - 64];
    for (int z = 0; z < nsplit; ++z)
        s += part2[(size_t)z * (N_SAMP * 128) + (size_t)n * 128 + t];
    const float sig = 1.0f / (1.0f + expf(-s));
    const int head = t >> 6, c = t & 63;
    pose_cls[(size_t)n * (NCLS * 2) + c * 2 + head] = sig;

    const unsigned long long mask = __ballot(s > 0.0f);
    if (c == 0) {
        const unsigned long long inv = ~mask;
        const int run = inv ? __builtin_ctzll(inv) : 64;
        const int lab = run - 1;
        esh[head] = lab > 0 ? lab : 0;
    }
    __syncthreads();

    const int e = esh[head];
    const int nk = head ? 4 : 3;
    for (int kk = 0; kk < nk; ++kk) {
        const float* wr = head ? wori + (size_t)(e * 4 + kk) * LATENT_D
                               : wpos + (size_t)(e * 3 + kk) * LATENT_D;
        const float bb = head ? bori[e * 4 + kk] : bpos[e * 3 + kk];
        const float4* w4 = reinterpret_cast<const float4*>(wr);
        float s2 = 0.f;
        #pragma unroll
        for (int i = 0; i < 4; ++i) {
            const int q = c + i * 64;
            const float4 a = w4[q];
            s2 += a.x * xs[q * 4] + a.y * xs[q * 4 + 1] + a.z * xs[q * 4 + 2] + a.w * xs[q * 4 + 3];
        }
        #pragma unroll
        for (int off = 32; off > 0; off >>= 1) s2 += __shfl_down(s2, off);
        if (c == 0) pose[(size_t)n * 7 + (head ? 3 + kk : kk)] = s2 + bb;
    }
}

// ---------------------------------------------------------------------------
extern "C" void kernel_launch(void* const* d_in, const int* in_sizes, int n_in,
                              void* d_out, int out_size, void* d_ws, size_t ws_size,
                              hipStream_t stream) {
    const float* feat   = (const float*)d_in[0];
    const float* fc1_w  = (const float*)d_in[1];
    const float* fc1_b  = (const float*)d_in[2];
    const float* cpw    = (const float*)d_in[3];
    const float* cpb    = (const float*)d_in[4];
    const float* cow    = (const float*)d_in[5];
    const float* cob    = (const float*)d_in[6];
    const float* rpw    = (const float*)d_in[7];
    const float* rpb    = (const float*)d_in[8];
    const float* row_   = (const float*)d_in[9];
    const float* rob    = (const float*)d_in[10];

    float* out = (float*)d_out;
    float* pose     = out;                          // [1024][7]
    float* pose_cls = out + (size_t)N_SAMP * 7;     // [1024][64][2]

    char* ws = (char*)d_ws;
    const size_t MB = (size_t)1 << 20;
    size_t off = 0;
    auto take = [&](size_t bytes) { char* p = ws + off; off += (bytes + 255) & ~(size_t)255; return p; };

    u16* A0 = (u16*)take(4 * MB);      // 64kg x 1024 x 32 x 2B
    u16* A1 = (u16*)take(4 * MB);
    u16* B0 = (u16*)take(4 * MB);
    u16* B1 = (u16*)take(4 * MB);
    u16* C0 = (u16*)take(256 * 1024);  // 32kg x 128 x 32 x 2B
    u16* C1 = (u16*)take(256 * 1024);
    u16* X0 = (u16*)take(2 * MB);      // 32kg x 1024 x 32 x 2B
    u16* X1 = (u16*)take(2 * MB);
    float* x = (float*)take(4 * MB);

    int nsplit = 4;
    while (nsplit > 1 && off + (size_t)nsplit * 4 * MB + 3 * MB > ws_size) nsplit >>= 1;
    float* part = (float*)take((size_t)nsplit * 4 * MB);
    int nsplit_c = 4;
    while (nsplit_c > 1 && off + (size_t)nsplit_c * 512 * 1024 > ws_size) nsplit_c >>= 1;
    float* part2 = (float*)take((size_t)nsplit_c * 512 * 1024);

    // 1. fused prep: pool->A splits, fc1_w->B splits, cls->C splits
    prep_kernel<<<16896, 256, 0, stream>>>(feat, fc1_w, cpw, cow,
                                           A0, A1, B0, B1, C0, C1);
    // 2. fc1: M=1024, N=1024, K=2048  (grid (8,8,4)=256 blocks, %8==0)
    split_mfma<<<dim3(8, 8, nsplit), 256, 0, stream>>>(
        A0, A1, B0, B1, part, 64 / nsplit, N_SAMP, LATENT_D, LATENT_D);
    // 3. reduce + bias + relu + x-split
    reduce_fc1<<<1024, 256, 0, stream>>>(part, fc1_b, x, X0, X1, nsplit);
    // 4. cls: M=1024, N=128, K=1024  (grid (2,16,4)=128 blocks, %8==0)
    cls_mfma<<<dim3(2, 16, nsplit_c), 256, 0, stream>>>(
        X0, X1, C0, C1, part2, 32 / nsplit_c);
    // 5. decode + expert
    decode_expert<<<N_SAMP, 128, 0, stream>>>(part2, cpb, cob, x, rpw, rpb, row_, rob,
                                              pose_cls, pose, nsplit_c);
}